// Round 5
// baseline (159.035 us; speedup 1.0000x reference)
//
#include <hip/hip_runtime.h>
#include <math.h>

#define BB 64
#define WW 128   // K (input feature dim per node)
#define FF 64    // nodes
#define HH 4
#define OW 128   // D (per-head output dim)

// ---------------------------------------------------------------------------
// Fully fused GAT, v5: LDS-pipe-slot economy.
// v4 accounting (validated: 88K LDS-slot cyc ~= 37 us + barriers = 46.5 us):
// broadcast LDS reads cost a full ~12-cyc slot. Fixes:
//  - Phase A: W operands straight from global (L2-resident, VMEM pipe idle),
//    register double-buffered; LDS keeps only x. A-LDS 24.6K -> 12.3K cyc,
//    A becomes fp32-FMA-bound (16.4K cyc floor).
//  - Phase D: 2-D register tile 4i x 4j per thread, d-halves split across
//    thread halves, partial merged via st2. 30.7K -> ~14K cyc.
//  - Phase F: 2-D register tile 4j x 8d per thread, i-halves split, merged
//    by the existing atomicAdd. 27.6K -> ~9.5K cyc.
// LDS ~107 KB (still 1 block/CU, which 91 KB already was); 512 threads;
// amdgpu_waves_per_eu(2,2) keeps the 256-VGPR budget (v3 spill lesson).
// ---------------------------------------------------------------------------

struct GemmRegion {
    float xq[64 * 68];          // [k-half 64][i 64 pad 68] 17.4 KB
};
struct AttnRegion {
    float fsl[FF * 132];        // [i][d] pad 132
    float fdl[FF * 132];        // [j][d] pad 132
    float st[FF * 68];          // [i][j] pad 68
    float st2[FF * 68];         // [i][j] pad 68 (D partial exchange)
    float A6[OW], B4[OW];       // 0.6*a_d, 0.4*a_d
    float redm[8 * 64];         // C: cs/cd partials (sel<4); E1: strip maxes
    float reds[8 * 64];         // E2: strip sums
};
union SMem { GemmRegion g; AttnRegion a; };

__global__ void __launch_bounds__(512)
__attribute__((amdgpu_waves_per_eu(2, 2)))
gat_fused(
    const float* __restrict__ x,     // [B][128 k][64 i]
    const float* __restrict__ Wsrc,  // [512][128]
    const float* __restrict__ bsrc,
    const float* __restrict__ Wdst,
    const float* __restrict__ bdst,
    const float* __restrict__ attn,  // [H][128]
    float* __restrict__ out)         // [B][128 d][64 j], pre-zeroed
{
    __shared__ __align__(16) SMem sm;
    __shared__ float bl[2 * 128];

    const int bx = blockIdx.x;
    const int h  = bx & 3;
    const int b  = bx >> 2;
    const int t  = threadIdx.x;

    // ---- phase A thread map (t < 256): m | ig(8) | dg(16) ----
    // outputs: i = ig*8 .. +7,  d = dg + 16*e (e = 0..7)
    const int m  = (t >> 7) & 1;
    const int ig = (t >> 4) & 7;
    const int dg = t & 15;
    const int i0 = ig * 8;

    if (t < 256) bl[t] = (t & 128 ? bdst : bsrc)[h * 128 + (t & 127)];

    // W row base for this thread's 8 d-rows (rows dg + 16e of the h-slice)
    const float* wbase = (m ? Wdst : Wsrc) + (size_t)(h * 128 + dg) * WW;

    float acc[8][8] = {};            // [ii][e]

    for (int kh = 0; kh < 2; ++kh) {
        if (kh) __syncthreads();
        // stage x half: [64 k][64 i] = 1024 float4, 2 per thread
        #pragma unroll
        for (int p = 0; p < 2; ++p) {
            const int idx = p * 512 + t;
            const int k = idx >> 4, iq = idx & 15;
            *(float4*)&sm.g.xq[k * 68 + iq * 4] =
                *(const float4*)(x + ((size_t)b * WW + kh * 64 + k) * FF + iq * 4);
        }
        __syncthreads();

        if (t < 256) {
            const float* wk = wbase + kh * 64;
            float4 wv[8];
            #pragma unroll
            for (int e = 0; e < 8; ++e)
                wv[e] = *(const float4*)(wk + (size_t)(16 * e) * WW);
            #pragma unroll 1
            for (int k0 = 0; k0 < 64; k0 += 4) {
                float4 wn[8];
                if (k0 < 60) {
                    #pragma unroll
                    for (int e = 0; e < 8; ++e)
                        wn[e] = *(const float4*)(wk + (size_t)(16 * e) * WW + k0 + 4);
                }
                #pragma unroll
                for (int kk = 0; kk < 4; ++kk) {
                    const float4 xa = *(const float4*)&sm.g.xq[(k0 + kk) * 68 + i0];
                    const float4 xb = *(const float4*)&sm.g.xq[(k0 + kk) * 68 + i0 + 4];
                    #pragma unroll
                    for (int e = 0; e < 8; ++e) {
                        const float wf = ((const float*)&wv[e])[kk];
                        acc[0][e] = fmaf(xa.x, wf, acc[0][e]);
                        acc[1][e] = fmaf(xa.y, wf, acc[1][e]);
                        acc[2][e] = fmaf(xa.z, wf, acc[2][e]);
                        acc[3][e] = fmaf(xa.w, wf, acc[3][e]);
                        acc[4][e] = fmaf(xb.x, wf, acc[4][e]);
                        acc[5][e] = fmaf(xb.y, wf, acc[5][e]);
                        acc[6][e] = fmaf(xb.z, wf, acc[6][e]);
                        acc[7][e] = fmaf(xb.w, wf, acc[7][e]);
                    }
                }
                #pragma unroll
                for (int e = 0; e < 8; ++e) wv[e] = wn[e];
            }
        }
    }
    __syncthreads();   // xq dead; attn region may now be written

    // ------------- phase B: acc+bias -> fsl/fdl, stage A6/B4 -------------
    if (t < 256) {
        float* dst = m ? sm.a.fdl : sm.a.fsl;
        #pragma unroll
        for (int e = 0; e < 8; ++e) {
            const int d = dg + 16 * e;
            const float bv = bl[m * 128 + d];
            #pragma unroll
            for (int ii = 0; ii < 8; ++ii)
                dst[(i0 + ii) * 132 + d] = acc[ii][e] + bv;
        }
    }
    if (t < 128) {
        const float av = attn[h * OW + t];
        sm.a.A6[t] = 0.6f * av;
        sm.a.B4[t] = 0.4f * av;
    }
    __syncthreads();

    // --------- phase C: cs/cd partials (256 threads, 2 halves each) ------
    // redm[sel*64+i]: sel 0,1 = fs halves; 2,3 = fd halves. Summed in D.
    if (t < 256) {
        const int i = t & 63, sel = t >> 6;
        const float* src = (sel < 2 ? sm.a.fsl : sm.a.fdl) + i * 132 + (sel & 1) * 64;
        const float* a6  = sm.a.A6 + (sel & 1) * 64;
        float s = 0.0f;
        #pragma unroll
        for (int c = 0; c < 16; ++c) {
            float4 fv = *(const float4*)&src[c * 4];
            float4 av = *(const float4*)&a6[c * 4];
            s = fmaf(fv.x, av.x, fmaf(fv.y, av.y, fmaf(fv.z, av.z, fmaf(fv.w, av.w, s))));
        }
        sm.a.redm[sel * 64 + i] = s;
    }
    __syncthreads();

    // -------- phase D: scores, 2-D register tile 4i x 4j, d-split --------
    // thread = (dh = t>>8, ig = t&15 -> 4 i, jg = (t>>4)&15 -> 4 j)
    {
        const int dh  = t >> 8;
        const int rem = t & 255;
        const int i0D = (rem & 15) * 4;
        const int j0D = (rem >> 4) * 4;
        float4 scq[4];                   // [ii]; components = jj
        scq[0] = scq[1] = scq[2] = scq[3] = float4{0.f, 0.f, 0.f, 0.f};
        const int cBase = dh * 16;
        #pragma unroll 4
        for (int c = 0; c < 16; ++c) {
            const int dd0 = (cBase + c) * 4;
            const float4 b4 = *(const float4*)&sm.a.B4[dd0];
            float4 fdv[4];
            #pragma unroll
            for (int jj = 0; jj < 4; ++jj)
                fdv[jj] = *(const float4*)&sm.a.fdl[(j0D + jj) * 132 + dd0];
            #pragma unroll
            for (int ii = 0; ii < 4; ++ii) {
                const float4 fsv = *(const float4*)&sm.a.fsl[(i0D + ii) * 132 + dd0];
                float* sc = (float*)&scq[ii];
                #pragma unroll
                for (int jj = 0; jj < 4; ++jj) {
                    float r = sc[jj];
                    r = fmaf(b4.x, fabsf(fsv.x + fdv[jj].x), r);
                    r = fmaf(b4.y, fabsf(fsv.y + fdv[jj].y), r);
                    r = fmaf(b4.z, fabsf(fsv.z + fdv[jj].z), r);
                    r = fmaf(b4.w, fabsf(fsv.w + fdv[jj].w), r);
                    sc[jj] = r;
                }
            }
        }
        if (dh) {
            #pragma unroll
            for (int ii = 0; ii < 4; ++ii)
                *(float4*)&sm.a.st2[(i0D + ii) * 68 + j0D] = scq[ii];
        }
        __syncthreads();
        if (!dh) {
            float cdj[4];
            #pragma unroll
            for (int jj = 0; jj < 4; ++jj)
                cdj[jj] = sm.a.redm[128 + j0D + jj] + sm.a.redm[192 + j0D + jj];
            #pragma unroll
            for (int ii = 0; ii < 4; ++ii) {
                const float4 p2 = *(const float4*)&sm.a.st2[(i0D + ii) * 68 + j0D];
                const float csl = sm.a.redm[i0D + ii] + sm.a.redm[64 + i0D + ii];
                float4 o;
                o.x = scq[ii].x + p2.x + csl + cdj[0];
                o.y = scq[ii].y + p2.y + csl + cdj[1];
                o.z = scq[ii].z + p2.z + csl + cdj[2];
                o.w = scq[ii].w + p2.w + csl + cdj[3];
                *(float4*)&sm.a.st[(i0D + ii) * 68 + j0D] = o;
            }
        }
    }
    __syncthreads();

    // --------------- phase E: softmax over i per j (8 strips) ------------
    {   // E1: per-strip max (8 strips of 8 i)
        const int j = t & 63, s = t >> 6;
        const int i0s = s * 8;
        float mx = sm.a.st[i0s * 68 + j];
        #pragma unroll
        for (int k = 1; k < 8; ++k) mx = fmaxf(mx, sm.a.st[(i0s + k) * 68 + j]);
        sm.a.redm[s * 64 + j] = mx;
    }
    __syncthreads();
    {   // E2: global max, exp in place, per-strip sum
        const int j = t & 63, s = t >> 6;
        const int i0s = s * 8;
        float mj = sm.a.redm[j];
        #pragma unroll
        for (int s2 = 1; s2 < 8; ++s2) mj = fmaxf(mj, sm.a.redm[s2 * 64 + j]);
        float ps = 0.0f;
        #pragma unroll
        for (int k = 0; k < 8; ++k) {
            float e = __expf(sm.a.st[(i0s + k) * 68 + j] - mj);
            sm.a.st[(i0s + k) * 68 + j] = e;
            ps += e;
        }
        sm.a.reds[s * 64 + j] = ps;
    }
    __syncthreads();

    // ------ phase F: aggregation, 2-D tile 4j x 8d, i-split + atomics ----
    // thread = (ih = t>>8, jg = t&15 -> 4 j, dgF = (t>>4)&15 -> 8 d)
    {
        const int ih  = t >> 8;
        const int rem = t & 255;
        const int j0F = (rem & 15) * 4;
        const int dF  = (rem >> 4) * 8;
        float iv[4];
        #pragma unroll
        for (int jj = 0; jj < 4; ++jj) {
            float l = 0.0f;
            #pragma unroll
            for (int s2 = 0; s2 < 8; ++s2) l += sm.a.reds[s2 * 64 + j0F + jj];
            iv[jj] = 0.25f / l;          // head-mean folded in
        }
        float ag[4][8] = {};             // [jj][dd]
        const int iBase = ih * 32;
        #pragma unroll 4
        for (int i2 = 0; i2 < 32; ++i2) {
            const int i = iBase + i2;
            const float4 pv = *(const float4*)&sm.a.st[i * 68 + j0F];   // 4 j
            const float* fr = &sm.a.fsl[i * 132 + dF];
            const float4 f0 = *(const float4*)(fr);
            const float4 f1 = *(const float4*)(fr + 4);
            const float* pp = (const float*)&pv;
            #pragma unroll
            for (int jj = 0; jj < 4; ++jj) {
                const float p = pp[jj];
                ag[jj][0] = fmaf(p, f0.x, ag[jj][0]);
                ag[jj][1] = fmaf(p, f0.y, ag[jj][1]);
                ag[jj][2] = fmaf(p, f0.z, ag[jj][2]);
                ag[jj][3] = fmaf(p, f0.w, ag[jj][3]);
                ag[jj][4] = fmaf(p, f1.x, ag[jj][4]);
                ag[jj][5] = fmaf(p, f1.y, ag[jj][5]);
                ag[jj][6] = fmaf(p, f1.z, ag[jj][6]);
                ag[jj][7] = fmaf(p, f1.w, ag[jj][7]);
            }
        }
        float* ob = out + ((size_t)b * OW + dF) * FF;
        #pragma unroll
        for (int jj = 0; jj < 4; ++jj) {
            #pragma unroll
            for (int dd = 0; dd < 8; ++dd)
                atomicAdd(ob + (size_t)dd * FF + j0F + jj, ag[jj][dd] * iv[jj]);
        }
    }
}

// ---------------------------------------------------------------------------
extern "C" void kernel_launch(void* const* d_in, const int* in_sizes, int n_in,
                              void* d_out, int out_size, void* d_ws, size_t ws_size,
                              hipStream_t stream) {
    const float* x    = (const float*)d_in[0];
    const float* Wsrc = (const float*)d_in[1];
    const float* bsrc = (const float*)d_in[2];
    const float* Wdst = (const float*)d_in[3];
    const float* bdst = (const float*)d_in[4];
    const float* attn = (const float*)d_in[5];

    hipMemsetAsync(d_out, 0, (size_t)out_size, stream);
    gat_fused<<<BB * HH, 512, 0, stream>>>(x, Wsrc, bsrc, Wdst, bdst, attn,
                                           (float*)d_out);
}

// Round 6
// 144.284 us; speedup vs baseline: 1.1022x; 1.1022x over previous
//
#include <hip/hip_runtime.h>
#include <math.h>

#define BB 64
#define WW 128   // K (input feature dim per node)
#define FF 64    // nodes
#define HH 4
#define OW 128   // D (per-head output dim)

// ---------------------------------------------------------------------------
// Fully fused GAT, v6 = v4's proven GEMM + v5's D/F register tiles with
// corrected bank geometry.
// v5 post-mortem: (1) A-phase W-from-global double-buffer spilled
// (WRITE_SIZE 65 MB scratch, VALUBusy 18%) -> revert A to v4 W-in-LDS
// (46.5 us, no spill). (2) D's 4-consecutive-i lane map was 8-way bank
// conflicted (4*132*ig mod 32 hits only {0,16}); F's stride-8 d map 4-way.
// Fixes:
//  - D: thread's 4 i = iT + 16*ii (lanes 0..15 hold i 0..15; 33*i mod 8
//    covers all 8 bank groups -> <=2-way on fsv reads and st/st2 writes).
//    2-D tile 4i x 4j x 64d-half; halves merged through st2.
//  - F: thread's 8 d = {dF..dF+3, dF+64..dF+67}, dF = 4*dgF: lane quads at
//    banks 0,4,..,60 -> 2-way (free). 4j x 8d over a 32-i half; halves
//    merged by the atomicAdd that already exists.
// LDS ~110 KB, 1 block/CU (as before); 512 threads; waves_per_eu(2,2).
// ---------------------------------------------------------------------------

struct GemmRegion {
    float xq[64 * 68];          // [k-half 64][i 64 pad 68] 17.4 KB
    float wq[2 * 128 * 68];     // [(m*128+d)][k 64 pad 68] 69.6 KB
};
struct AttnRegion {
    float fsl[FF * 132];        // [i][d] pad 132
    float fdl[FF * 132];        // [j][d] pad 132
    float st[FF * 68];          // [i][j] pad 68
    float st2[FF * 68];         // [i][j] pad 68 (D partial exchange)
    float A6[OW], B4[OW];       // 0.6*a_d, 0.4*a_d
    float redm[8 * 64];         // C: cs/cd partials; E1: strip maxes
    float reds[8 * 64];         // E2: strip sums
};
union SMem { GemmRegion g; AttnRegion a; };

__global__ void __launch_bounds__(512)
__attribute__((amdgpu_waves_per_eu(2, 2)))
gat_fused(
    const float* __restrict__ x,     // [B][128 k][64 i]
    const float* __restrict__ Wsrc,  // [512][128]
    const float* __restrict__ bsrc,
    const float* __restrict__ Wdst,
    const float* __restrict__ bdst,
    const float* __restrict__ attn,  // [H][128]
    float* __restrict__ out)         // [B][128 d][64 j], pre-zeroed
{
    __shared__ __align__(16) SMem sm;
    __shared__ float bl[2 * 128];

    const int bx = blockIdx.x;
    const int h  = bx & 3;
    const int b  = bx >> 2;
    const int t  = threadIdx.x;

    // ---- phase A thread map (t < 256): m | ig(8) | dg(16) ----
    // outputs: i = ig*8 .. +7,  d = dg + 16*e (e = 0..7)
    const int m  = (t >> 7) & 1;
    const int ig = (t >> 4) & 7;
    const int dg = t & 15;
    const int i0 = ig * 8;

    if (t < 256) bl[t] = (t & 128 ? bdst : bsrc)[h * 128 + (t & 127)];

    float acc[8][8] = {};            // [ii][e]

    for (int kh = 0; kh < 2; ++kh) {
        if (kh) __syncthreads();
        // stage x half: [64 k][64 i] = 1024 float4, 2 per thread
        #pragma unroll
        for (int p = 0; p < 2; ++p) {
            const int idx = p * 512 + t;
            const int k = idx >> 4, iq = idx & 15;
            *(float4*)&sm.g.xq[k * 68 + iq * 4] =
                *(const float4*)(x + ((size_t)b * WW + kh * 64 + k) * FF + iq * 4);
        }
        // stage W half: 2 mats x 128 d x 16 quads = 4096 float4, 8 per thread
        #pragma unroll
        for (int p = 0; p < 8; ++p) {
            const int idx = p * 512 + t;
            const int mm = idx >> 11, d = (idx >> 4) & 127, q = idx & 15;
            *(float4*)&sm.g.wq[(mm * 128 + d) * 68 + q * 4] =
                *(const float4*)((mm ? Wdst : Wsrc)
                                 + (size_t)(h * 128 + d) * WW + kh * 64 + q * 4);
        }
        __syncthreads();

        if (t < 256) {
            #pragma unroll 1
            for (int k0 = 0; k0 < 64; k0 += 4) {
                float4 wv[8];
                #pragma unroll
                for (int e = 0; e < 8; ++e)
                    wv[e] = *(const float4*)&sm.g.wq[(m * 128 + dg + 16 * e) * 68 + k0];
                #pragma unroll
                for (int kk = 0; kk < 4; ++kk) {
                    const float4 xa = *(const float4*)&sm.g.xq[(k0 + kk) * 68 + i0];
                    const float4 xb = *(const float4*)&sm.g.xq[(k0 + kk) * 68 + i0 + 4];
                    #pragma unroll
                    for (int e = 0; e < 8; ++e) {
                        const float wf = ((const float*)&wv[e])[kk];
                        acc[0][e] = fmaf(xa.x, wf, acc[0][e]);
                        acc[1][e] = fmaf(xa.y, wf, acc[1][e]);
                        acc[2][e] = fmaf(xa.z, wf, acc[2][e]);
                        acc[3][e] = fmaf(xa.w, wf, acc[3][e]);
                        acc[4][e] = fmaf(xb.x, wf, acc[4][e]);
                        acc[5][e] = fmaf(xb.y, wf, acc[5][e]);
                        acc[6][e] = fmaf(xb.z, wf, acc[6][e]);
                        acc[7][e] = fmaf(xb.w, wf, acc[7][e]);
                    }
                }
            }
        }
    }
    __syncthreads();   // GEMM region dead; attn region may now be written

    // ------------- phase B: acc+bias -> fsl/fdl, stage A6/B4 -------------
    if (t < 256) {
        float* dst = m ? sm.a.fdl : sm.a.fsl;
        #pragma unroll
        for (int e = 0; e < 8; ++e) {
            const int d = dg + 16 * e;
            const float bv = bl[m * 128 + d];
            #pragma unroll
            for (int ii = 0; ii < 8; ++ii)
                dst[(i0 + ii) * 132 + d] = acc[ii][e] + bv;
        }
    }
    if (t < 128) {
        const float av = attn[h * OW + t];
        sm.a.A6[t] = 0.6f * av;
        sm.a.B4[t] = 0.4f * av;
    }
    __syncthreads();

    // --------- phase C: cs/cd partials (256 threads, 2 halves each) ------
    // redm[sel*64+i]: sel 0,1 = fs halves; 2,3 = fd halves. Summed in D.
    if (t < 256) {
        const int i = t & 63, sel = t >> 6;
        const float* src = (sel < 2 ? sm.a.fsl : sm.a.fdl) + i * 132 + (sel & 1) * 64;
        const float* a6  = sm.a.A6 + (sel & 1) * 64;
        float s = 0.0f;
        #pragma unroll
        for (int c = 0; c < 16; ++c) {
            float4 fv = *(const float4*)&src[c * 4];
            float4 av = *(const float4*)&a6[c * 4];
            s = fmaf(fv.x, av.x, fmaf(fv.y, av.y, fmaf(fv.z, av.z, fmaf(fv.w, av.w, s))));
        }
        sm.a.redm[sel * 64 + i] = s;
    }
    __syncthreads();

    // -------- phase D: scores, 2-D tile 4i x 4j, d-halves via st2 --------
    // thread = (dh = t>>8, iT = t&15 -> i = iT+16*ii, jg -> 4 consecutive j)
    {
        const int dh  = t >> 8;
        const int rem = t & 255;
        const int iT  = rem & 15;
        const int j0D = (rem >> 4) * 4;
        float4 scq[4];                   // [ii]; components = jj
        scq[0] = scq[1] = scq[2] = scq[3] = float4{0.f, 0.f, 0.f, 0.f};
        const int cBase = dh * 16;
        #pragma unroll 4
        for (int c = 0; c < 16; ++c) {
            const int dd0 = (cBase + c) * 4;
            const float4 b4 = *(const float4*)&sm.a.B4[dd0];
            float4 fdv[4];
            #pragma unroll
            for (int jj = 0; jj < 4; ++jj)
                fdv[jj] = *(const float4*)&sm.a.fdl[(j0D + jj) * 132 + dd0];
            #pragma unroll
            for (int ii = 0; ii < 4; ++ii) {
                const float4 fsv =
                    *(const float4*)&sm.a.fsl[(iT + 16 * ii) * 132 + dd0];
                float* sc = (float*)&scq[ii];
                #pragma unroll
                for (int jj = 0; jj < 4; ++jj) {
                    float r = sc[jj];
                    r = fmaf(b4.x, fabsf(fsv.x + fdv[jj].x), r);
                    r = fmaf(b4.y, fabsf(fsv.y + fdv[jj].y), r);
                    r = fmaf(b4.z, fabsf(fsv.z + fdv[jj].z), r);
                    r = fmaf(b4.w, fabsf(fsv.w + fdv[jj].w), r);
                    sc[jj] = r;
                }
            }
        }
        if (dh) {
            #pragma unroll
            for (int ii = 0; ii < 4; ++ii)
                *(float4*)&sm.a.st2[(iT + 16 * ii) * 68 + j0D] = scq[ii];
        }
        __syncthreads();
        if (!dh) {
            float cdj[4];
            #pragma unroll
            for (int jj = 0; jj < 4; ++jj)
                cdj[jj] = sm.a.redm[128 + j0D + jj] + sm.a.redm[192 + j0D + jj];
            #pragma unroll
            for (int ii = 0; ii < 4; ++ii) {
                const int i = iT + 16 * ii;
                const float4 p2 = *(const float4*)&sm.a.st2[i * 68 + j0D];
                const float csl = sm.a.redm[i] + sm.a.redm[64 + i];
                float4 o;
                o.x = scq[ii].x + p2.x + csl + cdj[0];
                o.y = scq[ii].y + p2.y + csl + cdj[1];
                o.z = scq[ii].z + p2.z + csl + cdj[2];
                o.w = scq[ii].w + p2.w + csl + cdj[3];
                *(float4*)&sm.a.st[i * 68 + j0D] = o;
            }
        }
    }
    __syncthreads();

    // --------------- phase E: softmax over i per j (8 strips) ------------
    {   // E1: per-strip max (8 strips of 8 i)
        const int j = t & 63, s = t >> 6;
        const int i0s = s * 8;
        float mx = sm.a.st[i0s * 68 + j];
        #pragma unroll
        for (int k = 1; k < 8; ++k) mx = fmaxf(mx, sm.a.st[(i0s + k) * 68 + j]);
        sm.a.redm[s * 64 + j] = mx;
    }
    __syncthreads();
    {   // E2: global max, exp in place, per-strip sum
        const int j = t & 63, s = t >> 6;
        const int i0s = s * 8;
        float mj = sm.a.redm[j];
        #pragma unroll
        for (int s2 = 1; s2 < 8; ++s2) mj = fmaxf(mj, sm.a.redm[s2 * 64 + j]);
        float ps = 0.0f;
        #pragma unroll
        for (int k = 0; k < 8; ++k) {
            float e = __expf(sm.a.st[(i0s + k) * 68 + j] - mj);
            sm.a.st[(i0s + k) * 68 + j] = e;
            ps += e;
        }
        sm.a.reds[s * 64 + j] = ps;
    }
    __syncthreads();

    // ------ phase F: aggregation, 4j x 8d tile, i-halves via atomics -----
    // thread = (ih = t>>8, jg = t&15 -> 4 j, dgF -> d in {dF..+3, dF+64..+67})
    {
        const int ih  = t >> 8;
        const int rem = t & 255;
        const int j0F = (rem & 15) * 4;
        const int dF  = ((rem >> 4) & 15) * 4;
        float4 l4 = {0.f, 0.f, 0.f, 0.f};
        #pragma unroll
        for (int s2 = 0; s2 < 8; ++s2) {
            const float4 rv = *(const float4*)&sm.a.reds[s2 * 64 + j0F];
            l4.x += rv.x; l4.y += rv.y; l4.z += rv.z; l4.w += rv.w;
        }
        const float iv[4] = {0.25f / l4.x, 0.25f / l4.y, 0.25f / l4.z, 0.25f / l4.w};

        float ag[4][8] = {};             // [jj][dd]  dd<4 -> dF+dd, else dF+64+dd-4
        const int iBase = ih * 32;
        #pragma unroll 4
        for (int i2 = 0; i2 < 32; ++i2) {
            const int i = iBase + i2;
            const float4 pv = *(const float4*)&sm.a.st[i * 68 + j0F];   // 4 j
            const float4 f0 = *(const float4*)&sm.a.fsl[i * 132 + dF];
            const float4 f1 = *(const float4*)&sm.a.fsl[i * 132 + dF + 64];
            const float* pp = (const float*)&pv;
            #pragma unroll
            for (int jj = 0; jj < 4; ++jj) {
                const float p = pp[jj];
                ag[jj][0] = fmaf(p, f0.x, ag[jj][0]);
                ag[jj][1] = fmaf(p, f0.y, ag[jj][1]);
                ag[jj][2] = fmaf(p, f0.z, ag[jj][2]);
                ag[jj][3] = fmaf(p, f0.w, ag[jj][3]);
                ag[jj][4] = fmaf(p, f1.x, ag[jj][4]);
                ag[jj][5] = fmaf(p, f1.y, ag[jj][5]);
                ag[jj][6] = fmaf(p, f1.z, ag[jj][6]);
                ag[jj][7] = fmaf(p, f1.w, ag[jj][7]);
            }
        }
        float* ob = out + (size_t)b * OW * FF;
        #pragma unroll
        for (int jj = 0; jj < 4; ++jj) {
            #pragma unroll
            for (int k = 0; k < 4; ++k) {
                atomicAdd(ob + (size_t)(dF + k) * FF + j0F + jj,
                          ag[jj][k] * iv[jj]);
                atomicAdd(ob + (size_t)(dF + 64 + k) * FF + j0F + jj,
                          ag[jj][4 + k] * iv[jj]);
            }
        }
    }
}

// ---------------------------------------------------------------------------
extern "C" void kernel_launch(void* const* d_in, const int* in_sizes, int n_in,
                              void* d_out, int out_size, void* d_ws, size_t ws_size,
                              hipStream_t stream) {
    const float* x    = (const float*)d_in[0];
    const float* Wsrc = (const float*)d_in[1];
    const float* bsrc = (const float*)d_in[2];
    const float* Wdst = (const float*)d_in[3];
    const float* bdst = (const float*)d_in[4];
    const float* attn = (const float*)d_in[5];

    hipMemsetAsync(d_out, 0, (size_t)out_size, stream);
    gat_fused<<<BB * HH, 512, 0, stream>>>(x, Wsrc, bsrc, Wdst, bdst, attn,
                                           (float*)d_out);
}

// Round 7
// 102.574 us; speedup vs baseline: 1.5504x; 1.4066x over previous
//
#include <hip/hip_runtime.h>
#include <math.h>

#define BB 64
#define WW 128   // K (input feature dim per node)
#define FF 64    // nodes
#define HH 4
#define OW 128   // D (per-head output dim)

// ---------------------------------------------------------------------------
// Fully fused GAT, v7: dense atomics + transposed score matrix.
// v6 post-mortem: bank conflicts fixed (1.97M -> 155K) but F's atomic map
// scattered lanes at stride-16B -> every 4B atomic touched its own 64B
// sector (16.8 MB payload -> 65.5 MB HBM writes, RMW serialization).
// Changes vs v6 (A/B/C/D-compute kept verbatim):
//  - Scores stored TRANSPOSED: stT[j][i], pad 68 (17 quads == 1 mod 8 ->
//    conflict-free b128 rows). D's dh0 writer emits 16 b32 (2 lanes/bank).
//  - Phase E = single 64-thread row softmax: 16 b128 reads, reg max/exp/sum,
//    16 b128 writes, invl[j]. Deletes strip passes + redm/reds traffic.
//  - Phase F: 4j x 8d tile, j = jT + 16*jj (jT = lane&15): p-reads are b128
//    over 4 consecutive i (12 LDS slots / 4 i vs v4's 20); atomics per
//    instruction = 16 consecutive j x 4 d = 4 FULL 64B sectors; i-halves
//    combined through xfer LDS (stride 36, conflict-free) so atomic count
//    is back to v4's 2.1M (4 per output cell).
// LDS ~140 KB (1 block/CU as before); 512 threads; waves_per_eu(2,2).
// ---------------------------------------------------------------------------

struct GemmRegion {
    float xq[64 * 68];          // [k-half 64][i 64 pad 68] 17.4 KB
    float wq[2 * 128 * 68];     // [(m*128+d)][k 64 pad 68] 69.6 KB
};
struct AttnRegion {
    float fsl[FF * 132];        // [i][d] pad 132
    float fdl[FF * 132];        // [j][d] pad 132
    float stT[FF * 68];         // [j][i] pad 68  (TRANSPOSED scores)
    float st2[FF * 68];         // [i][j] pad 68  (D partial exchange)
    float A6[OW], B4[OW];       // 0.6*a_d, 0.4*a_d
    float redm[4 * 64];         // C: cs/cd partials
    float invl[64];             // 0.25 / l_j
    float xfer[256 * 36];       // F: i-half partial exchange (36.9 KB)
};
union SMem { GemmRegion g; AttnRegion a; };

__global__ void __launch_bounds__(512)
__attribute__((amdgpu_waves_per_eu(2, 2)))
gat_fused(
    const float* __restrict__ x,     // [B][128 k][64 i]
    const float* __restrict__ Wsrc,  // [512][128]
    const float* __restrict__ bsrc,
    const float* __restrict__ Wdst,
    const float* __restrict__ bdst,
    const float* __restrict__ attn,  // [H][128]
    float* __restrict__ out)         // [B][128 d][64 j], pre-zeroed
{
    __shared__ __align__(16) SMem sm;
    __shared__ float bl[2 * 128];

    const int bx = blockIdx.x;
    const int h  = bx & 3;
    const int b  = bx >> 2;
    const int t  = threadIdx.x;

    // ---- phase A thread map (t < 256): m | ig(8) | dg(16) ----
    // outputs: i = ig*8 .. +7,  d = dg + 16*e (e = 0..7)
    const int m  = (t >> 7) & 1;
    const int ig = (t >> 4) & 7;
    const int dg = t & 15;
    const int i0 = ig * 8;

    if (t < 256) bl[t] = (t & 128 ? bdst : bsrc)[h * 128 + (t & 127)];

    float acc[8][8] = {};            // [ii][e]

    for (int kh = 0; kh < 2; ++kh) {
        if (kh) __syncthreads();
        // stage x half: [64 k][64 i] = 1024 float4, 2 per thread
        #pragma unroll
        for (int p = 0; p < 2; ++p) {
            const int idx = p * 512 + t;
            const int k = idx >> 4, iq = idx & 15;
            *(float4*)&sm.g.xq[k * 68 + iq * 4] =
                *(const float4*)(x + ((size_t)b * WW + kh * 64 + k) * FF + iq * 4);
        }
        // stage W half: 2 mats x 128 d x 16 quads = 4096 float4, 8 per thread
        #pragma unroll
        for (int p = 0; p < 8; ++p) {
            const int idx = p * 512 + t;
            const int mm = idx >> 11, d = (idx >> 4) & 127, q = idx & 15;
            *(float4*)&sm.g.wq[(mm * 128 + d) * 68 + q * 4] =
                *(const float4*)((mm ? Wdst : Wsrc)
                                 + (size_t)(h * 128 + d) * WW + kh * 64 + q * 4);
        }
        __syncthreads();

        if (t < 256) {
            #pragma unroll 1
            for (int k0 = 0; k0 < 64; k0 += 4) {
                float4 wv[8];
                #pragma unroll
                for (int e = 0; e < 8; ++e)
                    wv[e] = *(const float4*)&sm.g.wq[(m * 128 + dg + 16 * e) * 68 + k0];
                #pragma unroll
                for (int kk = 0; kk < 4; ++kk) {
                    const float4 xa = *(const float4*)&sm.g.xq[(k0 + kk) * 68 + i0];
                    const float4 xb = *(const float4*)&sm.g.xq[(k0 + kk) * 68 + i0 + 4];
                    #pragma unroll
                    for (int e = 0; e < 8; ++e) {
                        const float wf = ((const float*)&wv[e])[kk];
                        acc[0][e] = fmaf(xa.x, wf, acc[0][e]);
                        acc[1][e] = fmaf(xa.y, wf, acc[1][e]);
                        acc[2][e] = fmaf(xa.z, wf, acc[2][e]);
                        acc[3][e] = fmaf(xa.w, wf, acc[3][e]);
                        acc[4][e] = fmaf(xb.x, wf, acc[4][e]);
                        acc[5][e] = fmaf(xb.y, wf, acc[5][e]);
                        acc[6][e] = fmaf(xb.z, wf, acc[6][e]);
                        acc[7][e] = fmaf(xb.w, wf, acc[7][e]);
                    }
                }
            }
        }
    }
    __syncthreads();   // GEMM region dead; attn region may now be written

    // ------------- phase B: acc+bias -> fsl/fdl, stage A6/B4 -------------
    if (t < 256) {
        float* dst = m ? sm.a.fdl : sm.a.fsl;
        #pragma unroll
        for (int e = 0; e < 8; ++e) {
            const int d = dg + 16 * e;
            const float bv = bl[m * 128 + d];
            #pragma unroll
            for (int ii = 0; ii < 8; ++ii)
                dst[(i0 + ii) * 132 + d] = acc[ii][e] + bv;
        }
    }
    if (t < 128) {
        const float av = attn[h * OW + t];
        sm.a.A6[t] = 0.6f * av;
        sm.a.B4[t] = 0.4f * av;
    }
    __syncthreads();

    // --------- phase C: cs/cd partials (256 threads, 2 halves each) ------
    // redm[sel*64+i]: sel 0,1 = fs halves; 2,3 = fd halves. Summed in D.
    if (t < 256) {
        const int i = t & 63, sel = t >> 6;
        const float* src = (sel < 2 ? sm.a.fsl : sm.a.fdl) + i * 132 + (sel & 1) * 64;
        const float* a6  = sm.a.A6 + (sel & 1) * 64;
        float s = 0.0f;
        #pragma unroll
        for (int c = 0; c < 16; ++c) {
            float4 fv = *(const float4*)&src[c * 4];
            float4 av = *(const float4*)&a6[c * 4];
            s = fmaf(fv.x, av.x, fmaf(fv.y, av.y, fmaf(fv.z, av.z, fmaf(fv.w, av.w, s))));
        }
        sm.a.redm[sel * 64 + i] = s;
    }
    __syncthreads();

    // -------- phase D: scores, 2-D tile 4i x 4j, d-halves via st2 --------
    // thread = (dh = t>>8, iT = t&15 -> i = iT+16*ii, jg -> 4 consecutive j)
    {
        const int dh  = t >> 8;
        const int rem = t & 255;
        const int iT  = rem & 15;
        const int j0D = (rem >> 4) * 4;
        float4 scq[4];                   // [ii]; components = jj
        scq[0] = scq[1] = scq[2] = scq[3] = float4{0.f, 0.f, 0.f, 0.f};
        const int cBase = dh * 16;
        #pragma unroll 4
        for (int c = 0; c < 16; ++c) {
            const int dd0 = (cBase + c) * 4;
            const float4 b4 = *(const float4*)&sm.a.B4[dd0];
            float4 fdv[4];
            #pragma unroll
            for (int jj = 0; jj < 4; ++jj)
                fdv[jj] = *(const float4*)&sm.a.fdl[(j0D + jj) * 132 + dd0];
            #pragma unroll
            for (int ii = 0; ii < 4; ++ii) {
                const float4 fsv =
                    *(const float4*)&sm.a.fsl[(iT + 16 * ii) * 132 + dd0];
                float* sc = (float*)&scq[ii];
                #pragma unroll
                for (int jj = 0; jj < 4; ++jj) {
                    float r = sc[jj];
                    r = fmaf(b4.x, fabsf(fsv.x + fdv[jj].x), r);
                    r = fmaf(b4.y, fabsf(fsv.y + fdv[jj].y), r);
                    r = fmaf(b4.z, fabsf(fsv.z + fdv[jj].z), r);
                    r = fmaf(b4.w, fabsf(fsv.w + fdv[jj].w), r);
                    sc[jj] = r;
                }
            }
        }
        if (dh) {
            #pragma unroll
            for (int ii = 0; ii < 4; ++ii)
                *(float4*)&sm.a.st2[(iT + 16 * ii) * 68 + j0D] = scq[ii];
        }
        __syncthreads();
        if (!dh) {
            float cdj[4];
            #pragma unroll
            for (int jj = 0; jj < 4; ++jj)
                cdj[jj] = sm.a.redm[128 + j0D + jj] + sm.a.redm[192 + j0D + jj];
            #pragma unroll
            for (int ii = 0; ii < 4; ++ii) {
                const int i = iT + 16 * ii;
                const float4 p2 = *(const float4*)&sm.a.st2[i * 68 + j0D];
                const float csl = sm.a.redm[i] + sm.a.redm[64 + i];
                const float* sc = (const float*)&scq[ii];
                const float* pp = (const float*)&p2;
                // transposed store: stT[j][i], banks (l&15)+16*(l>>4) -> 2/bank
                #pragma unroll
                for (int jj = 0; jj < 4; ++jj)
                    sm.a.stT[(j0D + jj) * 68 + i] = sc[jj] + pp[jj] + csl + cdj[jj];
            }
        }
    }
    __syncthreads();

    // ------- phase E: row softmax, one thread per j (64 threads) ---------
    if (t < 64) {
        const int j = t;
        float* row = &sm.a.stT[j * 68];
        float4 rv[16];
        float mx = -3.0e38f;
        #pragma unroll
        for (int q = 0; q < 16; ++q) {
            rv[q] = *(const float4*)&row[q * 4];
            mx = fmaxf(mx, fmaxf(fmaxf(rv[q].x, rv[q].y), fmaxf(rv[q].z, rv[q].w)));
        }
        float s = 0.0f;
        #pragma unroll
        for (int q = 0; q < 16; ++q) {
            float4 e;
            e.x = __expf(rv[q].x - mx);
            e.y = __expf(rv[q].y - mx);
            e.z = __expf(rv[q].z - mx);
            e.w = __expf(rv[q].w - mx);
            s += e.x + e.y + e.z + e.w;
            *(float4*)&row[q * 4] = e;
        }
        sm.a.invl[j] = 0.25f / s;        // head-mean folded in
    }
    __syncthreads();

    // ---- phase F: aggregation 4j x 8d, j strided; dense sector atomics ---
    // thread = (ih = t>>8, jT = rem&15, dgF = rem>>4): j = jT+16*jj,
    // d in {dF..dF+3, dF+64..dF+67}, dF = 4*dgF. Atomic instr = 16
    // consecutive j x 4 d = 4 full 64B sectors.
    {
        const int ih  = t >> 8;
        const int rem = t & 255;
        const int jT  = rem & 15;
        const int dgF = rem >> 4;
        const int dF  = dgF * 4;
        const int iBase = ih * 32;

        float ag[4][8] = {};             // [jj][dd] dd<4: dF+dd ; else dF+64+dd-4
        #pragma unroll 2
        for (int i2 = 0; i2 < 32; i2 += 4) {
            float4 pq[4];                // [jj] = p over 4 consecutive i
            #pragma unroll
            for (int jj = 0; jj < 4; ++jj)
                pq[jj] = *(const float4*)&sm.a.stT[(jT + 16 * jj) * 68 + iBase + i2];
            #pragma unroll
            for (int u = 0; u < 4; ++u) {
                const int i = iBase + i2 + u;
                const float4 f0 = *(const float4*)&sm.a.fsl[i * 132 + dF];
                const float4 f1 = *(const float4*)&sm.a.fsl[i * 132 + dF + 64];
                #pragma unroll
                for (int jj = 0; jj < 4; ++jj) {
                    const float p = ((const float*)&pq[jj])[u];
                    ag[jj][0] = fmaf(p, f0.x, ag[jj][0]);
                    ag[jj][1] = fmaf(p, f0.y, ag[jj][1]);
                    ag[jj][2] = fmaf(p, f0.z, ag[jj][2]);
                    ag[jj][3] = fmaf(p, f0.w, ag[jj][3]);
                    ag[jj][4] = fmaf(p, f1.x, ag[jj][4]);
                    ag[jj][5] = fmaf(p, f1.y, ag[jj][5]);
                    ag[jj][6] = fmaf(p, f1.z, ag[jj][6]);
                    ag[jj][7] = fmaf(p, f1.w, ag[jj][7]);
                }
            }
        }

        // i-half combine through LDS (stride 36 floats = 9 quads, free)
        if (ih) {
            #pragma unroll
            for (int jj = 0; jj < 4; ++jj) {
                float4 a0 = {ag[jj][0], ag[jj][1], ag[jj][2], ag[jj][3]};
                float4 a1 = {ag[jj][4], ag[jj][5], ag[jj][6], ag[jj][7]};
                *(float4*)&sm.a.xfer[rem * 36 + jj * 8]     = a0;
                *(float4*)&sm.a.xfer[rem * 36 + jj * 8 + 4] = a1;
            }
        }
        __syncthreads();
        if (!ih) {
            float* ob = out + (size_t)b * OW * FF;
            #pragma unroll
            for (int jj = 0; jj < 4; ++jj) {
                const float4 a0 = *(const float4*)&sm.a.xfer[rem * 36 + jj * 8];
                const float4 a1 = *(const float4*)&sm.a.xfer[rem * 36 + jj * 8 + 4];
                const float iv = sm.a.invl[jT + 16 * jj];
                const int j = jT + 16 * jj;
                atomicAdd(ob + (size_t)(dF + 0) * FF + j, (ag[jj][0] + a0.x) * iv);
                atomicAdd(ob + (size_t)(dF + 1) * FF + j, (ag[jj][1] + a0.y) * iv);
                atomicAdd(ob + (size_t)(dF + 2) * FF + j, (ag[jj][2] + a0.z) * iv);
                atomicAdd(ob + (size_t)(dF + 3) * FF + j, (ag[jj][3] + a0.w) * iv);
                atomicAdd(ob + (size_t)(dF + 64) * FF + j, (ag[jj][4] + a1.x) * iv);
                atomicAdd(ob + (size_t)(dF + 65) * FF + j, (ag[jj][5] + a1.y) * iv);
                atomicAdd(ob + (size_t)(dF + 66) * FF + j, (ag[jj][6] + a1.z) * iv);
                atomicAdd(ob + (size_t)(dF + 67) * FF + j, (ag[jj][7] + a1.w) * iv);
            }
        }
    }
}

// ---------------------------------------------------------------------------
extern "C" void kernel_launch(void* const* d_in, const int* in_sizes, int n_in,
                              void* d_out, int out_size, void* d_ws, size_t ws_size,
                              hipStream_t stream) {
    const float* x    = (const float*)d_in[0];
    const float* Wsrc = (const float*)d_in[1];
    const float* bsrc = (const float*)d_in[2];
    const float* Wdst = (const float*)d_in[3];
    const float* bdst = (const float*)d_in[4];
    const float* attn = (const float*)d_in[5];

    hipMemsetAsync(d_out, 0, (size_t)out_size, stream);
    gat_fused<<<BB * HH, 512, 0, stream>>>(x, Wsrc, bsrc, Wdst, bdst, attn,
                                           (float*)d_out);
}

// Round 8
// 101.079 us; speedup vs baseline: 1.5734x; 1.0148x over previous
//
#include <hip/hip_runtime.h>
#include <math.h>

#define BB 64
#define WW 128   // K (input feature dim per node)
#define FF 64    // nodes
#define HH 4
#define OW 128   // D (per-head output dim)

// ---------------------------------------------------------------------------
// Fully fused GAT, v8: fix phase-A pipe serialization.
// v7 post-mortem: per-phase instruction cuts landed (WRITE 13.8MB, conflicts
// 147K) but wall stuck at 44us: VALU 44K cyc + LDS 53K cyc ~= the 105K wall,
// i.e. the pipes SERIALIZE. Phase A had 1 compute-wave/SIMD (t<256), so every
// lgkmcnt wait was exposed; A alone ~45K cyc.
// Changes vs v7 (D/E/F byte-identical):
//  - Phase A on ALL 512 threads (2 waves/SIMD co-issue): tile 4i x 8d.
//  - x operand read DIRECT FROM GLOBAL (one 64B L1-resident line per k per
//    wave; 4-address multicast) -> x staging + xq region deleted; A's LDS
//    traffic is wv-only (2048 instrs); x rides the idle VMEM pipe.
//  - W stays LDS-staged in 64-k halves (wq pad 68: wv reads <=2-way).
// Expected: A wall ~26K cyc -> kernel ~35us.
// ---------------------------------------------------------------------------

struct GemmRegion {
    float wq[2 * 128 * 68];     // [(m*128+d)][k 64 pad 68] 69.6 KB
};
struct AttnRegion {
    float fsl[FF * 132];        // [i][d] pad 132
    float fdl[FF * 132];        // [j][d] pad 132
    float stT[FF * 68];         // [j][i] pad 68  (TRANSPOSED scores)
    float st2[FF * 68];         // [i][j] pad 68  (D partial exchange)
    float A6[OW], B4[OW];       // 0.6*a_d, 0.4*a_d
    float redm[4 * 64];         // C: cs/cd partials
    float invl[64];             // 0.25 / l_j
    float xfer[256 * 36];       // F: i-half partial exchange (36.9 KB)
};
union SMem { GemmRegion g; AttnRegion a; };

__global__ void __launch_bounds__(512)
__attribute__((amdgpu_waves_per_eu(2, 2)))
gat_fused(
    const float* __restrict__ x,     // [B][128 k][64 i]
    const float* __restrict__ Wsrc,  // [512][128]
    const float* __restrict__ bsrc,
    const float* __restrict__ Wdst,
    const float* __restrict__ bdst,
    const float* __restrict__ attn,  // [H][128]
    float* __restrict__ out)         // [B][128 d][64 j], pre-zeroed
{
    __shared__ __align__(16) SMem sm;
    __shared__ float bl[2 * 128];

    const int bx = blockIdx.x;
    const int h  = bx & 3;
    const int b  = bx >> 2;
    const int t  = threadIdx.x;

    // ---- phase A thread map (ALL 512): m | ig(16 x 4 rows) | dg(16) ----
    // outputs: row i = ig*4 .. +3 of (m ? fd : fs), d = dg + 16*e (e = 0..7)
    const int m  = t >> 8;
    const int ig = (t >> 4) & 15;
    const int dg = t & 15;
    const int i0 = ig * 4;

    if (t < 256) bl[t] = (t & 128 ? bdst : bsrc)[h * 128 + (t & 127)];

    const float* xb = x + (size_t)b * (WW * FF);   // [128 k][64 node]

    float acc[4][8] = {};            // [ii][e]

    for (int kh = 0; kh < 2; ++kh) {
        if (kh) __syncthreads();
        // stage W half: 2 mats x 128 d x 16 quads = 4096 float4, 8 per thread
        #pragma unroll
        for (int p = 0; p < 8; ++p) {
            const int idx = p * 512 + t;
            const int mm = idx >> 11, d = (idx >> 4) & 127, q = idx & 15;
            *(float4*)&sm.g.wq[(mm * 128 + d) * 68 + q * 4] =
                *(const float4*)((mm ? Wdst : Wsrc)
                                 + (size_t)(h * 128 + d) * WW + kh * 64 + q * 4);
        }
        __syncthreads();

        const float* xk = xb + (size_t)(kh * 64) * FF + i0;
        #pragma unroll 1
        for (int k0 = 0; k0 < 64; k0 += 4) {
            float4 wv[8];
            #pragma unroll
            for (int e = 0; e < 8; ++e)
                wv[e] = *(const float4*)&sm.g.wq[(m * 128 + dg + 16 * e) * 68 + k0];
            #pragma unroll
            for (int kk = 0; kk < 4; ++kk) {
                const float4 xv = *(const float4*)(xk + (size_t)(k0 + kk) * FF);
                #pragma unroll
                for (int e = 0; e < 8; ++e) {
                    const float wf = ((const float*)&wv[e])[kk];
                    acc[0][e] = fmaf(xv.x, wf, acc[0][e]);
                    acc[1][e] = fmaf(xv.y, wf, acc[1][e]);
                    acc[2][e] = fmaf(xv.z, wf, acc[2][e]);
                    acc[3][e] = fmaf(xv.w, wf, acc[3][e]);
                }
            }
        }
    }
    __syncthreads();   // GEMM region dead; attn region may now be written

    // ------------- phase B: acc+bias -> fsl/fdl, stage A6/B4 -------------
    {
        float* dst = m ? sm.a.fdl : sm.a.fsl;
        #pragma unroll
        for (int e = 0; e < 8; ++e) {
            const int d = dg + 16 * e;
            const float bv = bl[m * 128 + d];
            #pragma unroll
            for (int ii = 0; ii < 4; ++ii)
                dst[(i0 + ii) * 132 + d] = acc[ii][e] + bv;
        }
    }
    if (t < 128) {
        const float av = attn[h * OW + t];
        sm.a.A6[t] = 0.6f * av;
        sm.a.B4[t] = 0.4f * av;
    }
    __syncthreads();

    // --------- phase C: cs/cd partials (256 threads, 2 halves each) ------
    // redm[sel*64+i]: sel 0,1 = fs halves; 2,3 = fd halves. Summed in D.
    if (t < 256) {
        const int i = t & 63, sel = t >> 6;
        const float* src = (sel < 2 ? sm.a.fsl : sm.a.fdl) + i * 132 + (sel & 1) * 64;
        const float* a6  = sm.a.A6 + (sel & 1) * 64;
        float s = 0.0f;
        #pragma unroll
        for (int c = 0; c < 16; ++c) {
            float4 fv = *(const float4*)&src[c * 4];
            float4 av = *(const float4*)&a6[c * 4];
            s = fmaf(fv.x, av.x, fmaf(fv.y, av.y, fmaf(fv.z, av.z, fmaf(fv.w, av.w, s))));
        }
        sm.a.redm[sel * 64 + i] = s;
    }
    __syncthreads();

    // -------- phase D: scores, 2-D tile 4i x 4j, d-halves via st2 --------
    // thread = (dh = t>>8, iT = t&15 -> i = iT+16*ii, jg -> 4 consecutive j)
    {
        const int dh  = t >> 8;
        const int rem = t & 255;
        const int iT  = rem & 15;
        const int j0D = (rem >> 4) * 4;
        float4 scq[4];                   // [ii]; components = jj
        scq[0] = scq[1] = scq[2] = scq[3] = float4{0.f, 0.f, 0.f, 0.f};
        const int cBase = dh * 16;
        #pragma unroll 4
        for (int c = 0; c < 16; ++c) {
            const int dd0 = (cBase + c) * 4;
            const float4 b4 = *(const float4*)&sm.a.B4[dd0];
            float4 fdv[4];
            #pragma unroll
            for (int jj = 0; jj < 4; ++jj)
                fdv[jj] = *(const float4*)&sm.a.fdl[(j0D + jj) * 132 + dd0];
            #pragma unroll
            for (int ii = 0; ii < 4; ++ii) {
                const float4 fsv =
                    *(const float4*)&sm.a.fsl[(iT + 16 * ii) * 132 + dd0];
                float* sc = (float*)&scq[ii];
                #pragma unroll
                for (int jj = 0; jj < 4; ++jj) {
                    float r = sc[jj];
                    r = fmaf(b4.x, fabsf(fsv.x + fdv[jj].x), r);
                    r = fmaf(b4.y, fabsf(fsv.y + fdv[jj].y), r);
                    r = fmaf(b4.z, fabsf(fsv.z + fdv[jj].z), r);
                    r = fmaf(b4.w, fabsf(fsv.w + fdv[jj].w), r);
                    sc[jj] = r;
                }
            }
        }
        if (dh) {
            #pragma unroll
            for (int ii = 0; ii < 4; ++ii)
                *(float4*)&sm.a.st2[(iT + 16 * ii) * 68 + j0D] = scq[ii];
        }
        __syncthreads();
        if (!dh) {
            float cdj[4];
            #pragma unroll
            for (int jj = 0; jj < 4; ++jj)
                cdj[jj] = sm.a.redm[128 + j0D + jj] + sm.a.redm[192 + j0D + jj];
            #pragma unroll
            for (int ii = 0; ii < 4; ++ii) {
                const int i = iT + 16 * ii;
                const float4 p2 = *(const float4*)&sm.a.st2[i * 68 + j0D];
                const float csl = sm.a.redm[i] + sm.a.redm[64 + i];
                const float* sc = (const float*)&scq[ii];
                const float* pp = (const float*)&p2;
                // transposed store: stT[j][i]
                #pragma unroll
                for (int jj = 0; jj < 4; ++jj)
                    sm.a.stT[(j0D + jj) * 68 + i] = sc[jj] + pp[jj] + csl + cdj[jj];
            }
        }
    }
    __syncthreads();

    // ------- phase E: row softmax, one thread per j (64 threads) ---------
    if (t < 64) {
        const int j = t;
        float* row = &sm.a.stT[j * 68];
        float4 rv[16];
        float mx = -3.0e38f;
        #pragma unroll
        for (int q = 0; q < 16; ++q) {
            rv[q] = *(const float4*)&row[q * 4];
            mx = fmaxf(mx, fmaxf(fmaxf(rv[q].x, rv[q].y), fmaxf(rv[q].z, rv[q].w)));
        }
        float s = 0.0f;
        #pragma unroll
        for (int q = 0; q < 16; ++q) {
            float4 e;
            e.x = __expf(rv[q].x - mx);
            e.y = __expf(rv[q].y - mx);
            e.z = __expf(rv[q].z - mx);
            e.w = __expf(rv[q].w - mx);
            s += e.x + e.y + e.z + e.w;
            *(float4*)&row[q * 4] = e;
        }
        sm.a.invl[j] = 0.25f / s;        // head-mean folded in
    }
    __syncthreads();

    // ---- phase F: aggregation 4j x 8d, j strided; dense sector atomics ---
    // thread = (ih = t>>8, jT = rem&15, dgF = rem>>4): j = jT+16*jj,
    // d in {dF..dF+3, dF+64..dF+67}, dF = 4*dgF.
    {
        const int ih  = t >> 8;
        const int rem = t & 255;
        const int jT  = rem & 15;
        const int dgF = rem >> 4;
        const int dF  = dgF * 4;
        const int iBase = ih * 32;

        float ag[4][8] = {};             // [jj][dd] dd<4: dF+dd ; else dF+64+dd-4
        #pragma unroll 2
        for (int i2 = 0; i2 < 32; i2 += 4) {
            float4 pq[4];                // [jj] = p over 4 consecutive i
            #pragma unroll
            for (int jj = 0; jj < 4; ++jj)
                pq[jj] = *(const float4*)&sm.a.stT[(jT + 16 * jj) * 68 + iBase + i2];
            #pragma unroll
            for (int u = 0; u < 4; ++u) {
                const int i = iBase + i2 + u;
                const float4 f0 = *(const float4*)&sm.a.fsl[i * 132 + dF];
                const float4 f1 = *(const float4*)&sm.a.fsl[i * 132 + dF + 64];
                #pragma unroll
                for (int jj = 0; jj < 4; ++jj) {
                    const float p = ((const float*)&pq[jj])[u];
                    ag[jj][0] = fmaf(p, f0.x, ag[jj][0]);
                    ag[jj][1] = fmaf(p, f0.y, ag[jj][1]);
                    ag[jj][2] = fmaf(p, f0.z, ag[jj][2]);
                    ag[jj][3] = fmaf(p, f0.w, ag[jj][3]);
                    ag[jj][4] = fmaf(p, f1.x, ag[jj][4]);
                    ag[jj][5] = fmaf(p, f1.y, ag[jj][5]);
                    ag[jj][6] = fmaf(p, f1.z, ag[jj][6]);
                    ag[jj][7] = fmaf(p, f1.w, ag[jj][7]);
                }
            }
        }

        // i-half combine through LDS (stride 36 floats = 9 quads, free)
        if (ih) {
            #pragma unroll
            for (int jj = 0; jj < 4; ++jj) {
                float4 a0 = {ag[jj][0], ag[jj][1], ag[jj][2], ag[jj][3]};
                float4 a1 = {ag[jj][4], ag[jj][5], ag[jj][6], ag[jj][7]};
                *(float4*)&sm.a.xfer[rem * 36 + jj * 8]     = a0;
                *(float4*)&sm.a.xfer[rem * 36 + jj * 8 + 4] = a1;
            }
        }
        __syncthreads();
        if (!ih) {
            float* ob = out + (size_t)b * OW * FF;
            #pragma unroll
            for (int jj = 0; jj < 4; ++jj) {
                const float4 a0 = *(const float4*)&sm.a.xfer[rem * 36 + jj * 8];
                const float4 a1 = *(const float4*)&sm.a.xfer[rem * 36 + jj * 8 + 4];
                const float iv = sm.a.invl[jT + 16 * jj];
                const int j = jT + 16 * jj;
                atomicAdd(ob + (size_t)(dF + 0) * FF + j, (ag[jj][0] + a0.x) * iv);
                atomicAdd(ob + (size_t)(dF + 1) * FF + j, (ag[jj][1] + a0.y) * iv);
                atomicAdd(ob + (size_t)(dF + 2) * FF + j, (ag[jj][2] + a0.z) * iv);
                atomicAdd(ob + (size_t)(dF + 3) * FF + j, (ag[jj][3] + a0.w) * iv);
                atomicAdd(ob + (size_t)(dF + 64) * FF + j, (ag[jj][4] + a1.x) * iv);
                atomicAdd(ob + (size_t)(dF + 65) * FF + j, (ag[jj][5] + a1.y) * iv);
                atomicAdd(ob + (size_t)(dF + 66) * FF + j, (ag[jj][6] + a1.z) * iv);
                atomicAdd(ob + (size_t)(dF + 67) * FF + j, (ag[jj][7] + a1.w) * iv);
            }
        }
    }
}

// ---------------------------------------------------------------------------
extern "C" void kernel_launch(void* const* d_in, const int* in_sizes, int n_in,
                              void* d_out, int out_size, void* d_ws, size_t ws_size,
                              hipStream_t stream) {
    const float* x    = (const float*)d_in[0];
    const float* Wsrc = (const float*)d_in[1];
    const float* bsrc = (const float*)d_in[2];
    const float* Wdst = (const float*)d_in[3];
    const float* bdst = (const float*)d_in[4];
    const float* attn = (const float*)d_in[5];

    hipMemsetAsync(d_out, 0, (size_t)out_size, stream);
    gat_fused<<<BB * HH, 512, 0, stream>>>(x, Wsrc, bsrc, Wdst, bdst, attn,
                                           (float*)d_out);
}

// Round 10
// 100.132 us; speedup vs baseline: 1.5882x; 1.0095x over previous
//
#include <hip/hip_runtime.h>
#include <math.h>

#define BB 64
#define WW 128   // K (input feature dim per node)
#define FF 64    // nodes
#define HH 4
#define OW 128   // D (per-head output dim)

// ---------------------------------------------------------------------------
// Fully fused GAT, v9 (resubmit — round-9 bench failed on container acquire,
// no counters; kernel unchanged to preserve the A/B vs round 8).
// v8 post-mortem: traffic is clean (conflicts 16K, WRITE 8.2MB, no spill)
// but wall 102K cyc vs 47K VALU issue -> exposed latency:
//  (a) A's k-loop was unroll-1-pinned: no software pipelining of the
//      8 ds_read_b128 + 4 global x loads; 2 waves/SIMD can't hide ~200cyc.
//  (b) E ran on 1 of 8 waves (serial chain fully exposed).
//  (c) A paid 4 barriers for 2 staging rounds.
// Changes vs v8 (B/C/D/F byte-identical):
//  - Stage BOTH W k-halves up front (wq 139KB; union still ~142KB, 1 blk/CU
//    unchanged). One barrier, single 32-iter k-loop over 128 k.
//  - k-loop unroll 2: compiler pipelines next iter's wv/xv under FMAs.
//    VGPR headroom: 88 now, 256 budget (waves_per_eu(2,2)).
//  - E parallelized on all 512 threads: 8 threads/row j, __shfl_xor
//    width-8 reductions, 2 b128 reads + 2 writes/thread, <=2-way banks.
// ---------------------------------------------------------------------------

struct GemmRegion {
    float wq[2 * 2 * 128 * 68]; // [(kh*256 + m*128 + d)][k 64 pad 68] 139 KB
};
struct AttnRegion {
    float fsl[FF * 132];        // [i][d] pad 132
    float fdl[FF * 132];        // [j][d] pad 132
    float stT[FF * 68];         // [j][i] pad 68  (TRANSPOSED scores)
    float st2[FF * 68];         // [i][j] pad 68  (D partial exchange)
    float A6[OW], B4[OW];       // 0.6*a_d, 0.4*a_d
    float redm[4 * 64];         // C: cs/cd partials
    float invl[64];             // 0.25 / l_j
    float xfer[256 * 36];       // F: i-half partial exchange (36.9 KB)
};
union SMem { GemmRegion g; AttnRegion a; };

__global__ void __launch_bounds__(512)
__attribute__((amdgpu_waves_per_eu(2, 2)))
gat_fused(
    const float* __restrict__ x,     // [B][128 k][64 i]
    const float* __restrict__ Wsrc,  // [512][128]
    const float* __restrict__ bsrc,
    const float* __restrict__ Wdst,
    const float* __restrict__ bdst,
    const float* __restrict__ attn,  // [H][128]
    float* __restrict__ out)         // [B][128 d][64 j], pre-zeroed
{
    __shared__ __align__(16) SMem sm;
    __shared__ float bl[2 * 128];

    const int bx = blockIdx.x;
    const int h  = bx & 3;
    const int b  = bx >> 2;
    const int t  = threadIdx.x;

    // ---- phase A thread map (ALL 512): m | ig(16 x 4 rows) | dg(16) ----
    // outputs: row i = ig*4 .. +3 of (m ? fd : fs), d = dg + 16*e (e = 0..7)
    const int m  = t >> 8;
    const int ig = (t >> 4) & 15;
    const int dg = t & 15;
    const int i0 = ig * 4;

    if (t < 256) bl[t] = (t & 128 ? bdst : bsrc)[h * 128 + (t & 127)];

    const float* xb = x + (size_t)b * (WW * FF);   // [128 k][64 node]

    // ---- stage BOTH W k-halves: 8192 float4, 16 per thread ----
    #pragma unroll
    for (int p = 0; p < 16; ++p) {
        const int idx = p * 512 + t;            // [kh 2][mm 2][d 128][q 16]
        const int kh = idx >> 12;
        const int mm = (idx >> 11) & 1;
        const int d  = (idx >> 4) & 127;
        const int q  = idx & 15;
        *(float4*)&sm.g.wq[((kh << 8) + mm * 128 + d) * 68 + q * 4] =
            *(const float4*)((mm ? Wdst : Wsrc)
                             + (size_t)(h * 128 + d) * WW + kh * 64 + q * 4);
    }
    __syncthreads();

    float acc[4][8] = {};            // [ii][e]
    {
        const int wrow = m * 128 + dg;          // + 16*e
        #pragma unroll 2
        for (int k0 = 0; k0 < 128; k0 += 4) {
            const int kq = k0 >> 6;             // which k-half
            const int kw = k0 & 63;             // k within half
            float4 wv[8];
            #pragma unroll
            for (int e = 0; e < 8; ++e)
                wv[e] = *(const float4*)&sm.g.wq[((kq << 8) + wrow + 16 * e) * 68 + kw];
            #pragma unroll
            for (int kk = 0; kk < 4; ++kk) {
                const float4 xv = *(const float4*)(xb + (size_t)(k0 + kk) * FF + i0);
                #pragma unroll
                for (int e = 0; e < 8; ++e) {
                    const float wf = ((const float*)&wv[e])[kk];
                    acc[0][e] = fmaf(xv.x, wf, acc[0][e]);
                    acc[1][e] = fmaf(xv.y, wf, acc[1][e]);
                    acc[2][e] = fmaf(xv.z, wf, acc[2][e]);
                    acc[3][e] = fmaf(xv.w, wf, acc[3][e]);
                }
            }
        }
    }
    __syncthreads();   // GEMM region dead; attn region may now be written

    // ------------- phase B: acc+bias -> fsl/fdl, stage A6/B4 -------------
    {
        float* dst = m ? sm.a.fdl : sm.a.fsl;
        #pragma unroll
        for (int e = 0; e < 8; ++e) {
            const int d = dg + 16 * e;
            const float bv = bl[m * 128 + d];
            #pragma unroll
            for (int ii = 0; ii < 4; ++ii)
                dst[(i0 + ii) * 132 + d] = acc[ii][e] + bv;
        }
    }
    if (t < 128) {
        const float av = attn[h * OW + t];
        sm.a.A6[t] = 0.6f * av;
        sm.a.B4[t] = 0.4f * av;
    }
    __syncthreads();

    // --------- phase C: cs/cd partials (256 threads, 2 halves each) ------
    // redm[sel*64+i]: sel 0,1 = fs halves; 2,3 = fd halves. Summed in D.
    if (t < 256) {
        const int i = t & 63, sel = t >> 6;
        const float* src = (sel < 2 ? sm.a.fsl : sm.a.fdl) + i * 132 + (sel & 1) * 64;
        const float* a6  = sm.a.A6 + (sel & 1) * 64;
        float s = 0.0f;
        #pragma unroll
        for (int c = 0; c < 16; ++c) {
            float4 fv = *(const float4*)&src[c * 4];
            float4 av = *(const float4*)&a6[c * 4];
            s = fmaf(fv.x, av.x, fmaf(fv.y, av.y, fmaf(fv.z, av.z, fmaf(fv.w, av.w, s))));
        }
        sm.a.redm[sel * 64 + i] = s;
    }
    __syncthreads();

    // -------- phase D: scores, 2-D tile 4i x 4j, d-halves via st2 --------
    // thread = (dh = t>>8, iT = t&15 -> i = iT+16*ii, jg -> 4 consecutive j)
    {
        const int dh  = t >> 8;
        const int rem = t & 255;
        const int iT  = rem & 15;
        const int j0D = (rem >> 4) * 4;
        float4 scq[4];                   // [ii]; components = jj
        scq[0] = scq[1] = scq[2] = scq[3] = float4{0.f, 0.f, 0.f, 0.f};
        const int cBase = dh * 16;
        #pragma unroll 4
        for (int c = 0; c < 16; ++c) {
            const int dd0 = (cBase + c) * 4;
            const float4 b4 = *(const float4*)&sm.a.B4[dd0];
            float4 fdv[4];
            #pragma unroll
            for (int jj = 0; jj < 4; ++jj)
                fdv[jj] = *(const float4*)&sm.a.fdl[(j0D + jj) * 132 + dd0];
            #pragma unroll
            for (int ii = 0; ii < 4; ++ii) {
                const float4 fsv =
                    *(const float4*)&sm.a.fsl[(iT + 16 * ii) * 132 + dd0];
                float* sc = (float*)&scq[ii];
                #pragma unroll
                for (int jj = 0; jj < 4; ++jj) {
                    float r = sc[jj];
                    r = fmaf(b4.x, fabsf(fsv.x + fdv[jj].x), r);
                    r = fmaf(b4.y, fabsf(fsv.y + fdv[jj].y), r);
                    r = fmaf(b4.z, fabsf(fsv.z + fdv[jj].z), r);
                    r = fmaf(b4.w, fabsf(fsv.w + fdv[jj].w), r);
                    sc[jj] = r;
                }
            }
        }
        if (dh) {
            #pragma unroll
            for (int ii = 0; ii < 4; ++ii)
                *(float4*)&sm.a.st2[(iT + 16 * ii) * 68 + j0D] = scq[ii];
        }
        __syncthreads();
        if (!dh) {
            float cdj[4];
            #pragma unroll
            for (int jj = 0; jj < 4; ++jj)
                cdj[jj] = sm.a.redm[128 + j0D + jj] + sm.a.redm[192 + j0D + jj];
            #pragma unroll
            for (int ii = 0; ii < 4; ++ii) {
                const int i = iT + 16 * ii;
                const float4 p2 = *(const float4*)&sm.a.st2[i * 68 + j0D];
                const float csl = sm.a.redm[i] + sm.a.redm[64 + i];
                const float* sc = (const float*)&scq[ii];
                const float* pp = (const float*)&p2;
                // transposed store: stT[j][i]
                #pragma unroll
                for (int jj = 0; jj < 4; ++jj)
                    sm.a.stT[(j0D + jj) * 68 + i] = sc[jj] + pp[jj] + csl + cdj[jj];
            }
        }
    }
    __syncthreads();

    // ------- phase E: row softmax, 8 threads per j (all 512 threads) -----
    {
        const int j   = t >> 3;          // row
        const int sub = t & 7;           // i-slice: 8 consecutive i
        float* rp = &sm.a.stT[j * 68 + sub * 8];
        float4 r0 = *(const float4*)(rp);
        float4 r1 = *(const float4*)(rp + 4);
        float mx = fmaxf(fmaxf(fmaxf(r0.x, r0.y), fmaxf(r0.z, r0.w)),
                         fmaxf(fmaxf(r1.x, r1.y), fmaxf(r1.z, r1.w)));
        #pragma unroll
        for (int o = 1; o < 8; o <<= 1) mx = fmaxf(mx, __shfl_xor(mx, o));
        float4 e0, e1;
        e0.x = __expf(r0.x - mx); e0.y = __expf(r0.y - mx);
        e0.z = __expf(r0.z - mx); e0.w = __expf(r0.w - mx);
        e1.x = __expf(r1.x - mx); e1.y = __expf(r1.y - mx);
        e1.z = __expf(r1.z - mx); e1.w = __expf(r1.w - mx);
        float s = e0.x + e0.y + e0.z + e0.w + e1.x + e1.y + e1.z + e1.w;
        #pragma unroll
        for (int o = 1; o < 8; o <<= 1) s += __shfl_xor(s, o);
        *(float4*)(rp)     = e0;
        *(float4*)(rp + 4) = e1;
        if (sub == 0) sm.a.invl[j] = 0.25f / s;   // head-mean folded in
    }
    __syncthreads();

    // ---- phase F: aggregation 4j x 8d, j strided; dense sector atomics ---
    // thread = (ih = t>>8, jT = rem&15, dgF = rem>>4): j = jT+16*jj,
    // d in {dF..dF+3, dF+64..dF+67}, dF = 4*dgF.
    {
        const int ih  = t >> 8;
        const int rem = t & 255;
        const int jT  = rem & 15;
        const int dgF = rem >> 4;
        const int dF  = dgF * 4;
        const int iBase = ih * 32;

        float ag[4][8] = {};             // [jj][dd] dd<4: dF+dd ; else dF+64+dd-4
        #pragma unroll 2
        for (int i2 = 0; i2 < 32; i2 += 4) {
            float4 pq[4];                // [jj] = p over 4 consecutive i
            #pragma unroll
            for (int jj = 0; jj < 4; ++jj)
                pq[jj] = *(const float4*)&sm.a.stT[(jT + 16 * jj) * 68 + iBase + i2];
            #pragma unroll
            for (int u = 0; u < 4; ++u) {
                const int i = iBase + i2 + u;
                const float4 f0 = *(const float4*)&sm.a.fsl[i * 132 + dF];
                const float4 f1 = *(const float4*)&sm.a.fsl[i * 132 + dF + 64];
                #pragma unroll
                for (int jj = 0; jj < 4; ++jj) {
                    const float p = ((const float*)&pq[jj])[u];
                    ag[jj][0] = fmaf(p, f0.x, ag[jj][0]);
                    ag[jj][1] = fmaf(p, f0.y, ag[jj][1]);
                    ag[jj][2] = fmaf(p, f0.z, ag[jj][2]);
                    ag[jj][3] = fmaf(p, f0.w, ag[jj][3]);
                    ag[jj][4] = fmaf(p, f1.x, ag[jj][4]);
                    ag[jj][5] = fmaf(p, f1.y, ag[jj][5]);
                    ag[jj][6] = fmaf(p, f1.z, ag[jj][6]);
                    ag[jj][7] = fmaf(p, f1.w, ag[jj][7]);
                }
            }
        }

        // i-half combine through LDS (stride 36 floats = 9 quads, free)
        if (ih) {
            #pragma unroll
            for (int jj = 0; jj < 4; ++jj) {
                float4 a0 = {ag[jj][0], ag[jj][1], ag[jj][2], ag[jj][3]};
                float4 a1 = {ag[jj][4], ag[jj][5], ag[jj][6], ag[jj][7]};
                *(float4*)&sm.a.xfer[rem * 36 + jj * 8]     = a0;
                *(float4*)&sm.a.xfer[rem * 36 + jj * 8 + 4] = a1;
            }
        }
        __syncthreads();
        if (!ih) {
            float* ob = out + (size_t)b * OW * FF;
            #pragma unroll
            for (int jj = 0; jj < 4; ++jj) {
                const float4 a0 = *(const float4*)&sm.a.xfer[rem * 36 + jj * 8];
                const float4 a1 = *(const float4*)&sm.a.xfer[rem * 36 + jj * 8 + 4];
                const float iv = sm.a.invl[jT + 16 * jj];
                const int j = jT + 16 * jj;
                atomicAdd(ob + (size_t)(dF + 0) * FF + j, (ag[jj][0] + a0.x) * iv);
                atomicAdd(ob + (size_t)(dF + 1) * FF + j, (ag[jj][1] + a0.y) * iv);
                atomicAdd(ob + (size_t)(dF + 2) * FF + j, (ag[jj][2] + a0.z) * iv);
                atomicAdd(ob + (size_t)(dF + 3) * FF + j, (ag[jj][3] + a0.w) * iv);
                atomicAdd(ob + (size_t)(dF + 64) * FF + j, (ag[jj][4] + a1.x) * iv);
                atomicAdd(ob + (size_t)(dF + 65) * FF + j, (ag[jj][5] + a1.y) * iv);
                atomicAdd(ob + (size_t)(dF + 66) * FF + j, (ag[jj][6] + a1.z) * iv);
                atomicAdd(ob + (size_t)(dF + 67) * FF + j, (ag[jj][7] + a1.w) * iv);
            }
        }
    }
}

// ---------------------------------------------------------------------------
extern "C" void kernel_launch(void* const* d_in, const int* in_sizes, int n_in,
                              void* d_out, int out_size, void* d_ws, size_t ws_size,
                              hipStream_t stream) {
    const float* x    = (const float*)d_in[0];
    const float* Wsrc = (const float*)d_in[1];
    const float* bsrc = (const float*)d_in[2];
    const float* Wdst = (const float*)d_in[3];
    const float* bdst = (const float*)d_in[4];
    const float* attn = (const float*)d_in[5];

    hipMemsetAsync(d_out, 0, (size_t)out_size, stream);
    gat_fused<<<BB * HH, 512, 0, stream>>>(x, Wsrc, bsrc, Wdst, bdst, attn,
                                           (float*)d_out);
}